// Round 2
// baseline (204.854 us; speedup 1.0000x reference)
//
#include <hip/hip_runtime.h>
#include <hip/hip_bf16.h>

#define B_ 1024
#define S_ 100
#define IN_ 100
#define H_ 128
#define MID_ 32
#define OUT_ 2
#define P_ (B_ * S_)
#define RSQRT_H 0.08838834764831845f
#define LSTR 136   // 272 B row stride: benign 2-way max conflicts for b128 tile reads
#define HSTR 136

// LDS pool (ushort units):
//   R0 [100][136] = 13600 : x -> kq -> P(banded softmax) -> mid
//   R1 [100][136] = 13600 : h -> ctx
//   R2 [128][136] = 17408 : scores f32 [100][8] (head, 3.2KB) -> hvT
#define R1_OFF 13600
#define R2_OFF 27200
#define POOL_SHORTS (27200 + 17408)  // 89216 B -> 1 block/CU, 16 waves

typedef __attribute__((ext_vector_type(8))) short short8;
typedef __attribute__((ext_vector_type(4))) short short4v;
typedef __attribute__((ext_vector_type(4))) float float4v;

__device__ __forceinline__ float bf2f(ushort u) {
    union { unsigned u; float f; } c; c.u = ((unsigned)u) << 16; return c.f;
}
__device__ __forceinline__ ushort f2bf(float x) {
    union { float f; unsigned u; } c; c.f = x;
    unsigned r = c.u + 0x7FFFu + ((c.u >> 16) & 1u);  // RNE
    return (ushort)(r >> 16);
}

// banded score tiles: |m0-n0| <= 17 over tile starts {0,16,32,48,64,80,84}
__device__ const int BAND_M0[19] = {0,0,16,16,16,32,32,32,48,48,48,64,64,64,80,80,80,84,84};
__device__ const int BAND_N0[19] = {0,16,0,16,32,16,32,48,32,48,64,48,64,80,64,80,84,80,84};

// C[m0+4q+i][n0+l15] = sum_{ks0..ks1} A[m][k] * Bt[n][k], 16x16x32 bf16 MFMA
__device__ __forceinline__ float4v gemm_task(const ushort* A, int astr,
                                             const ushort* Bt, int bstr,
                                             int m0, int n0, int ks0, int ks1,
                                             int l15, int quad) {
    float4v acc = {0.f, 0.f, 0.f, 0.f};
    const ushort* ap = A + (m0 + l15) * astr + quad * 8;
    const ushort* bp = Bt + (n0 + l15) * bstr + quad * 8;
    for (int ks = ks0; ks <= ks1; ++ks) {
        short8 a = *(const short8*)(ap + ks * 32);
        short8 b = *(const short8*)(bp + ks * 32);
        acc = __builtin_amdgcn_mfma_f32_16x16x32_bf16(a, b, acc, 0, 0, 0);
    }
    return acc;
}

// ---------------------------------------------------------------------------
// Merged prep (unchanged): blocks 0..143 transpose W1/Wv/W2; 144..159 WqkT.
// ---------------------------------------------------------------------------
__global__ __launch_bounds__(256) void prep_kernel(
    const float* __restrict__ W1, const float* __restrict__ Wv,
    const float* __restrict__ W2, const float* __restrict__ Wq,
    const float* __restrict__ Wk,
    ushort* __restrict__ W1T, ushort* __restrict__ WvT,
    ushort* __restrict__ W2T, ushort* __restrict__ WqkT) {
    int tid = threadIdx.x;
    if (blockIdx.x < 144) {
        int g = blockIdx.x * 256 + tid;
        if (g < 16384) {
            int n = g >> 7, k = g & 127;
            W1T[g] = (k < IN_) ? f2bf(W1[k * H_ + n]) : (ushort)0;
        } else if (g < 32768) {
            int e = g - 16384; int n = e >> 7, k = e & 127;
            WvT[e] = f2bf(Wv[k * H_ + n]);
        } else {
            int e = g - 32768; int n = e >> 7, k = e & 127;
            W2T[e] = f2bf(W2[k * MID_ + n]);
        }
    } else {
        __shared__ float sq[32][132];
        __shared__ float sk[32][132];
        int bid = blockIdx.x - 144;
        int n0 = (bid >> 2) * 32, k0 = (bid & 3) * 32;
        for (int i = tid; i < 32 * 32; i += 256) {
            int r = i >> 5, c4 = (i & 31) * 4;
            float4 a = *(const float4*)(Wq + (k0 + r) * H_ + c4);
            float4 b = *(const float4*)(Wk + (n0 + r) * H_ + c4);
            sq[r][c4] = a.x; sq[r][c4 + 1] = a.y; sq[r][c4 + 2] = a.z; sq[r][c4 + 3] = a.w;
            sk[r][c4] = b.x; sk[r][c4 + 1] = b.y; sk[r][c4 + 2] = b.z; sk[r][c4 + 3] = b.w;
        }
        __syncthreads();
        for (int i = tid; i < 1024; i += 256) {
            int kk = i & 31, nn = i >> 5;
            float a0 = 0.f, a1 = 0.f, a2 = 0.f, a3 = 0.f;
#pragma unroll
            for (int j = 0; j < 128; j += 4) {
                a0 += sq[kk][j + 0] * sk[nn][j + 0];
                a1 += sq[kk][j + 1] * sk[nn][j + 1];
                a2 += sq[kk][j + 2] * sk[nn][j + 2];
                a3 += sq[kk][j + 3] * sk[nn][j + 3];
            }
            WqkT[(n0 + nn) * 128 + (k0 + kk)] = f2bf((a0 + a1) + (a2 + a3));
        }
    }
}

// ---------------------------------------------------------------------------
// Megakernel: one block (1024 threads, 16 waves) per batch row. All phases
// after the x-load are MFMA GEMMs; softmax is the only remaining VALU phase.
// ---------------------------------------------------------------------------
__global__ __launch_bounds__(1024, 4) void fused_kernel(
    const float* __restrict__ x, const ushort* __restrict__ W1T,
    const ushort* __restrict__ WqkT, const ushort* __restrict__ WvT,
    const ushort* __restrict__ W2T,
    const float* __restrict__ b1, const float* __restrict__ bv,
    const float* __restrict__ b2, const float* __restrict__ W3,
    const float* __restrict__ b3, const float* __restrict__ pe,
    float* __restrict__ out, float* __restrict__ wout) {
    __shared__ __align__(16) ushort pool[POOL_SHORTS];
    ushort* R0 = pool;
    ushort* R1 = pool + R1_OFF;
    ushort* R2 = pool + R2_OFF;
    float* scf = (float*)R2;  // [100][8] f32, overlays hvT head (dead before P5)

    int tid = threadIdx.x, wave = tid >> 6, lane = tid & 63;
    int l15 = lane & 15, quad = lane >> 4;
    int b = blockIdx.x;
    const float* xb = x + (size_t)b * (S_ * IN_);

    // P0: x -> R0 bf16 [m][k] (float4 loads, rows of 25 vec4); zero K-pad
    // cols 100..127; zero the score buffer (invalid neighbors must score 0).
    for (int i = tid; i < 2500; i += 1024) {
        float4 v = ((const float4*)xb)[i];
        int m = i / 25, k4 = (i - m * 25) * 4;
        short4v s;
        s[0] = (short)f2bf(v.x); s[1] = (short)f2bf(v.y);
        s[2] = (short)f2bf(v.z); s[3] = (short)f2bf(v.w);
        *(short4v*)(R0 + m * LSTR + k4) = s;
    }
    for (int i = tid; i < S_ * 28; i += 1024) {
        int r = i / 28, c = i - r * 28;
        R0[r * LSTR + 100 + c] = 0;
    }
    if (tid < 800) scf[tid] = 0.f;
    __syncthreads();

    // P1: h = relu(x@W1 + b1) + pe -> R1   (7 Mt x 8 Nt = 56 tasks)
    for (int t = wave; t < 56; t += 16) {
        int mt = t >> 3, nt = t & 7;
        int m0 = (mt < 6) ? mt * 16 : 84, n0 = nt * 16;
        float4v acc = gemm_task(R0, LSTR, W1T, 128, m0, n0, 0, 3, l15, quad);
        int n = n0 + l15;
        float bb = b1[n];
#pragma unroll
        for (int i = 0; i < 4; ++i) {
            int row = m0 + quad * 4 + i;
            R1[row * LSTR + n] = f2bf(fmaxf(acc[i] + bb, 0.f) + pe[row * H_ + n]);
        }
    }
    __syncthreads();

    // P2: kq = h @ (Wq Wk^T) -> R0 (x dead)
    for (int t = wave; t < 56; t += 16) {
        int mt = t >> 3, nt = t & 7;
        int m0 = (mt < 6) ? mt * 16 : 84, n0 = nt * 16;
        float4v acc = gemm_task(R1, LSTR, WqkT, 128, m0, n0, 0, 3, l15, quad);
        int n = n0 + l15;
#pragma unroll
        for (int i = 0; i < 4; ++i)
            R0[(m0 + quad * 4 + i) * LSTR + n] = f2bf(acc[i]);
    }
    __syncthreads();

    // P3: banded score tiles S[r][c] = kq[r] . h[c]  (19 tiles on the band).
    // Epilogue scatters band elements (m = r-c+2 in [0,4]) into scf[r][m].
    // Overlap tiles (80/84) duplicate rows 84-95 with identical values: benign.
    for (int t = wave; t < 19; t += 16) {
        int m0 = BAND_M0[t], n0 = BAND_N0[t];
        float4v acc = gemm_task(R0, LSTR, R1, LSTR, m0, n0, 0, 3, l15, quad);
        int col = n0 + l15;
#pragma unroll
        for (int i = 0; i < 4; ++i) {
            int row = m0 + quad * 4 + i;
            int m = row - col + 2;
            if ((unsigned)m <= 4u) scf[row * 8 + m] = acc[i];
        }
    }
    __syncthreads();

    // P4a: zero P (R0 cols 0..127; kq dead)
    {
        short8 z = {0, 0, 0, 0, 0, 0, 0, 0};
        for (int i = tid; i < 1600; i += 1024)
            *(short8*)(R0 + (i >> 4) * LSTR + (i & 15) * 8) = z;
    }
    __syncthreads();
    // P4b: softmax over the 5 band scores; write wout + banded P (bf16)
    if (tid < S_) {
        int r = tid;
        float sc5[5];
#pragma unroll
        for (int m = 0; m < 5; ++m) sc5[m] = scf[r * 8 + m] * RSQRT_H;
        float mx = fmaxf(fmaxf(fmaxf(sc5[0], sc5[1]), fmaxf(sc5[2], sc5[3])), sc5[4]);
        float e[5], ss = 0.f;
#pragma unroll
        for (int m = 0; m < 5; ++m) { e[m] = expf(sc5[m] - mx); ss += e[m]; }
        float inv = 1.f / ss;
        float* wp = wout + (size_t)b * (S_ * 5) + r * 5;
#pragma unroll
        for (int m = 0; m < 5; ++m) {
            float w = e[m] * inv;
            wp[m] = w;
            int c = r + 2 - m;
            if (0 <= c && c < S_) R0[r * LSTR + c] = f2bf(w);
        }
    }
    __syncthreads();

    // P5: hvT[j][c] = sum_h WvT[j][h] * h[c][h] -> R2 (scf dead).
    // A = WvT (global, row-major [j][h]); B = h rows. 8 Mt x 7 Nt = 56 tasks.
    for (int t = wave; t < 56; t += 16) {
        int nt = t >> 3, mt = t & 7;
        int m0 = mt * 16, n0 = (nt < 6) ? nt * 16 : 84;
        float4v acc = gemm_task(WvT, 128, R1, LSTR, m0, n0, 0, 3, l15, quad);
        int c = n0 + l15;
#pragma unroll
        for (int i = 0; i < 4; ++i)
            R2[(m0 + quad * 4 + i) * HSTR + c] = f2bf(acc[i]);
    }
    // zero hvT pad cols 100..127 (read by ks=3 of P6; garbage could be NaN)
    for (int i = tid; i < 128 * 28; i += 1024) {
        int r = i / 28, c = i - r * 28;
        R2[r * HSTR + 100 + c] = 0;
    }
    __syncthreads();

    // P6: ctx = P @ hvT^T + bv -> R1 (h dead). Band => only ks where the
    // 32-col K-slice intersects [m0-2, m0+19] (1-2 of 4 K-steps per M-tile).
    for (int t = wave; t < 56; t += 16) {
        int mt = t >> 3, nt = t & 7;
        int m0 = (mt < 6) ? mt * 16 : 84, n0 = nt * 16;
        int ks0 = (m0 - 2) >> 5; if (ks0 < 0) ks0 = 0;
        int ks1 = (m0 + 19) >> 5; if (ks1 > 3) ks1 = 3;
        float4v acc = gemm_task(R0, LSTR, R2, HSTR, m0, n0, ks0, ks1, l15, quad);
        int n = n0 + l15;
        float bb = bv[n];
#pragma unroll
        for (int i = 0; i < 4; ++i)
            R1[(m0 + quad * 4 + i) * LSTR + n] = f2bf(acc[i] + bb);
    }
    __syncthreads();

    // P7: mid = relu(ctx @ W2 + b2) -> R0 cols 0..31 (P dead). 14 tasks.
    for (int t = wave; t < 14; t += 16) {
        int mt = t >> 1, nt = t & 1;
        int m0 = (mt < 6) ? mt * 16 : 84, n0 = nt * 16;
        float4v acc = gemm_task(R1, LSTR, W2T, 128, m0, n0, 0, 3, l15, quad);
        int n = n0 + l15;
        float bb = b2[n];
#pragma unroll
        for (int i = 0; i < 4; ++i)
            R0[(m0 + quad * 4 + i) * LSTR + n] = f2bf(fmaxf(acc[i] + bb, 0.f));
    }
    __syncthreads();

    // P8: out = mid @ W3 + b3 (K=32, N=2), vector math on 100 threads.
    if (tid < S_) {
        int r = tid;
        float o0 = b3[0], o1 = b3[1];
#pragma unroll
        for (int c8 = 0; c8 < 4; ++c8) {
            short8 v = *(const short8*)(R0 + r * LSTR + c8 * 8);
#pragma unroll
            for (int j = 0; j < 8; ++j) {
                float mv = bf2f((ushort)v[j]);
                int k = c8 * 8 + j;
                o0 += mv * W3[k * 2];
                o1 += mv * W3[k * 2 + 1];
            }
        }
        float* op = out + (size_t)b * (S_ * OUT_) + r * OUT_;
        op[0] = o0; op[1] = o1;
    }
}

// ---------------------------------------------------------------------------
extern "C" void kernel_launch(void* const* d_in, const int* in_sizes, int n_in,
                              void* d_out, int out_size, void* d_ws, size_t ws_size,
                              hipStream_t stream) {
    const float* x  = (const float*)d_in[0];
    const float* W1 = (const float*)d_in[1];
    const float* b1 = (const float*)d_in[2];
    const float* Wq = (const float*)d_in[3];
    const float* Wk = (const float*)d_in[4];
    const float* Wv = (const float*)d_in[5];
    const float* bv = (const float*)d_in[6];
    const float* W2 = (const float*)d_in[7];
    const float* b2 = (const float*)d_in[8];
    const float* W3 = (const float*)d_in[9];
    const float* b3 = (const float*)d_in[10];
    const float* pe = (const float*)d_in[11];

    float* out  = (float*)d_out;             // (B,S,2)
    float* wout = out + (size_t)P_ * OUT_;   // (B,S,1,5)

    ushort* W1T  = (ushort*)d_ws;            // [128][128] bf16
    ushort* WqkT = W1T + 16384;              // [128][128] bf16
    ushort* WvT  = WqkT + 16384;             // [128][128] bf16
    ushort* W2T  = WvT + 16384;              // [32][128]  bf16

    prep_kernel<<<160, 256, 0, stream>>>(W1, Wv, W2, Wq, Wk, W1T, WvT, W2T, WqkT);
    fused_kernel<<<B_, 1024, 0, stream>>>(x, W1T, WqkT, WvT, W2T,
                                          b1, bv, b2, W3, b3, pe, out, wout);
}

// Round 3
// 135.945 us; speedup vs baseline: 1.5069x; 1.5069x over previous
//
#include <hip/hip_runtime.h>
#include <hip/hip_bf16.h>

#define B_ 1024
#define S_ 100
#define IN_ 100
#define H_ 128
#define MID_ 32
#define OUT_ 2
#define P_ (B_ * S_)
#define RSQRT_H 0.08838834764831845f
#define LSTR 136   // LDS row stride in bf16 elems: 272 B -> max 2-way bank conflict (free)

typedef __attribute__((ext_vector_type(8))) short short8;
typedef __attribute__((ext_vector_type(4))) short short4v;
typedef __attribute__((ext_vector_type(4))) float float4v;

__device__ __forceinline__ float bf2f(ushort u) {
    union { unsigned u; float f; } c; c.u = ((unsigned)u) << 16; return c.f;
}
__device__ __forceinline__ ushort f2bf(float x) {
    union { float f; unsigned u; } c; c.f = x;
    unsigned r = c.u + 0x7FFFu + ((c.u >> 16) & 1u);  // RNE
    return (ushort)(r >> 16);
}

// banded score tiles: |m0-n0| <= 17 over tile starts {0,16,32,48,64,80,84}
__device__ const int BAND_M0[19] = {0,0,16,16,16,32,32,32,48,48,48,64,64,64,80,80,80,84,84};
__device__ const int BAND_N0[19] = {0,16,0,16,32,16,32,48,32,48,64,48,64,80,64,80,84,80,84};

// ---------------------------------------------------------------------------
// Merged prep: blocks 0..143 transpose W1/Wv/W2 -> bf16 [n][k] (k padded 128);
// blocks 144..159 compute WqkT[n][k] = sum_j Wq[k][j]*Wk[n][j] (32x32 tiles).
// ---------------------------------------------------------------------------
__global__ __launch_bounds__(256) void prep_kernel(
    const float* __restrict__ W1, const float* __restrict__ Wv,
    const float* __restrict__ W2, const float* __restrict__ Wq,
    const float* __restrict__ Wk,
    ushort* __restrict__ W1T, ushort* __restrict__ WvT,
    ushort* __restrict__ W2T, ushort* __restrict__ WqkT) {
    int tid = threadIdx.x;
    if (blockIdx.x < 144) {
        int g = blockIdx.x * 256 + tid;
        if (g < 16384) {
            int n = g >> 7, k = g & 127;
            W1T[g] = (k < IN_) ? f2bf(W1[k * H_ + n]) : (ushort)0;
        } else if (g < 32768) {
            int e = g - 16384; int n = e >> 7, k = e & 127;
            WvT[e] = f2bf(Wv[k * H_ + n]);
        } else {
            int e = g - 32768; int n = e >> 7, k = e & 127;
            W2T[e] = f2bf(W2[k * MID_ + n]);
        }
    } else {
        __shared__ float sq[32][132];
        __shared__ float sk[32][132];
        int bid = blockIdx.x - 144;
        int n0 = (bid >> 2) * 32, k0 = (bid & 3) * 32;
        for (int i = tid; i < 32 * 32; i += 256) {
            int r = i >> 5, c4 = (i & 31) * 4;
            float4 a = *(const float4*)(Wq + (k0 + r) * H_ + c4);
            float4 b = *(const float4*)(Wk + (n0 + r) * H_ + c4);
            sq[r][c4] = a.x; sq[r][c4 + 1] = a.y; sq[r][c4 + 2] = a.z; sq[r][c4 + 3] = a.w;
            sk[r][c4] = b.x; sk[r][c4 + 1] = b.y; sk[r][c4 + 2] = b.z; sk[r][c4 + 3] = b.w;
        }
        __syncthreads();
        for (int i = tid; i < 1024; i += 256) {
            int kk = i & 31, nn = i >> 5;
            float a0 = 0.f, a1 = 0.f, a2 = 0.f, a3 = 0.f;
#pragma unroll
            for (int j = 0; j < 128; j += 4) {
                a0 += sq[kk][j + 0] * sk[nn][j + 0];
                a1 += sq[kk][j + 1] * sk[nn][j + 1];
                a2 += sq[kk][j + 2] * sk[nn][j + 2];
                a3 += sq[kk][j + 3] * sk[nn][j + 3];
            }
            WqkT[(n0 + nn) * 128 + (k0 + kk)] = f2bf((a0 + a1) + (a2 + a3));
        }
    }
}

// ---------------------------------------------------------------------------
// Fused per-sequence GEMM stage (R1-proven shape): 8 waves, one 16-col N-tile
// per wave, 7 M-tiles (starts 0,16,..,80,84; last overlaps rows 84-95 with
// identical duplicate writes -> benign). EPI 0: none | 1: relu+bias+pe | 2: +bias
// ---------------------------------------------------------------------------
template <int EPI>
__device__ __forceinline__ void mm_stage(const ushort* __restrict__ A_lds,
                                         const ushort* __restrict__ WT,
                                         ushort* __restrict__ C_lds,
                                         int wave, int lane,
                                         const float* __restrict__ bias,
                                         const float* __restrict__ pe) {
    int l15 = lane & 15, quad = lane >> 4;
    int n = wave * 16 + l15;
    short8 bfrag[4];
#pragma unroll
    for (int ks = 0; ks < 4; ++ks)
        bfrag[ks] = *(const short8*)(WT + n * 128 + ks * 32 + quad * 8);
    float biasv = 0.f;
    if (EPI != 0) biasv = bias[n];
#pragma unroll
    for (int mt = 0; mt < 7; ++mt) {
        int m0 = (mt < 6) ? mt * 16 : 84;
        short8 afrag[4];
#pragma unroll
        for (int ks = 0; ks < 4; ++ks)
            afrag[ks] = *(const short8*)(A_lds + (m0 + l15) * LSTR + ks * 32 + quad * 8);
        float4v acc = {0.f, 0.f, 0.f, 0.f};
#pragma unroll
        for (int ks = 0; ks < 4; ++ks)
            acc = __builtin_amdgcn_mfma_f32_16x16x32_bf16(afrag[ks], bfrag[ks], acc, 0, 0, 0);
#pragma unroll
        for (int i = 0; i < 4; ++i) {
            int row = m0 + quad * 4 + i;
            float v = acc[i];
            if (EPI == 1) v = fmaxf(v + biasv, 0.f) + pe[row * H_ + n];
            else if (EPI == 2) v = v + biasv;
            C_lds[row * LSTR + n] = f2bf(v);
        }
    }
}

// ---------------------------------------------------------------------------
// Megakernel: one block (512 threads, 8 waves, 57.6KB LDS -> 2 blocks/CU).
// ---------------------------------------------------------------------------
__global__ __launch_bounds__(512, 4) void fused_kernel(
    const float* __restrict__ x, const ushort* __restrict__ W1T,
    const ushort* __restrict__ WqkT, const ushort* __restrict__ WvT,
    const ushort* __restrict__ W2T,
    const float* __restrict__ b1, const float* __restrict__ bv,
    const float* __restrict__ b2, const float* __restrict__ W3,
    const float* __restrict__ b3, const float* __restrict__ pe,
    float* __restrict__ out, float* __restrict__ wout) {
    __shared__ __align__(16) ushort R0[S_ * LSTR];  // x -> kq -> nsum -> mid
    __shared__ __align__(16) ushort R1[S_ * LSTR];  // h -> ctx
    __shared__ float scf[S_ * 8];                   // banded scores f32

    int tid = threadIdx.x, wave = tid >> 6, lane = tid & 63;
    int l15 = lane & 15, quad = lane >> 4;
    int b = blockIdx.x;
    const float* xb = x + (size_t)b * (S_ * IN_);

    // P0: x -> R0 bf16 [m][k] (float4, 25 vec4 per row); zero K-pad cols;
    // zero scf (out-of-range neighbors must score 0, matching the reference).
    for (int i = tid; i < 2500; i += 512) {
        float4 v = ((const float4*)xb)[i];
        int m = i / 25, k4 = (i - m * 25) * 4;
        short4v s;
        s[0] = (short)f2bf(v.x); s[1] = (short)f2bf(v.y);
        s[2] = (short)f2bf(v.z); s[3] = (short)f2bf(v.w);
        *(short4v*)(R0 + m * LSTR + k4) = s;
    }
    for (int i = tid; i < S_ * 28; i += 512) {
        int r = i / 28, c = i - r * 28;
        R0[r * LSTR + 100 + c] = 0;
    }
    for (int i = tid; i < S_ * 8; i += 512) scf[i] = 0.f;
    __syncthreads();

    // P1: h = relu(x@W1 + b1) + pe -> R1
    mm_stage<1>(R0, W1T, R1, wave, lane, b1, pe);
    __syncthreads();

    // P2: kq = h @ (Wq Wk^T) -> R0 (x dead)
    mm_stage<0>(R1, WqkT, R0, wave, lane, nullptr, nullptr);
    __syncthreads();

    // P3: banded score tiles S[r][c] = kq[r].h[c] via MFMA (19 tiles on the
    // band); scatter band elements (m = r-c+2 in [0,4]) into scf[r][m].
    // Overlap tiles (80/84) duplicate rows 84-95 with identical values: benign.
    for (int t = wave; t < 19; t += 8) {
        int m0 = BAND_M0[t], n0 = BAND_N0[t];
        const ushort* ap = R0 + (m0 + l15) * LSTR + quad * 8;
        const ushort* bp = R1 + (n0 + l15) * LSTR + quad * 8;
        float4v acc = {0.f, 0.f, 0.f, 0.f};
#pragma unroll
        for (int ks = 0; ks < 4; ++ks) {
            short8 a = *(const short8*)(ap + ks * 32);
            short8 bb = *(const short8*)(bp + ks * 32);
            acc = __builtin_amdgcn_mfma_f32_16x16x32_bf16(a, bb, acc, 0, 0, 0);
        }
        int col = n0 + l15;
#pragma unroll
        for (int i = 0; i < 4; ++i) {
            int row = m0 + quad * 4 + i;
            int m = row - col + 2;
            if ((unsigned)m <= 4u) scf[row * 8 + m] = acc[i];
        }
    }
    __syncthreads();

    // P4: per-row softmax (recomputed by each of 4 threads/row from scf) +
    // nsum[r] = sum_m w[m]*h[r+2-m] -> R0 (kq dead). bv absorbed post-GEMM
    // (sum w = 1; padded neighbors have h = 0 so contribute only bv).
    if (tid < 4 * S_) {
        int r = tid >> 2, q = tid & 3;
        float sc5[5];
#pragma unroll
        for (int m = 0; m < 5; ++m) sc5[m] = scf[r * 8 + m] * RSQRT_H;
        float mx = fmaxf(fmaxf(fmaxf(sc5[0], sc5[1]), fmaxf(sc5[2], sc5[3])), sc5[4]);
        float e[5], ss = 0.f;
#pragma unroll
        for (int m = 0; m < 5; ++m) { e[m] = expf(sc5[m] - mx); ss += e[m]; }
        float inv = 1.f / ss;
        float w5[5];
#pragma unroll
        for (int m = 0; m < 5; ++m) w5[m] = e[m] * inv;
        if (q == 0) {
            float* wp = wout + (size_t)b * (S_ * 5) + r * 5;
#pragma unroll
            for (int m = 0; m < 5; ++m) wp[m] = w5[m];
        }
        float acc[32];
#pragma unroll
        for (int c = 0; c < 32; ++c) acc[c] = 0.f;
#pragma unroll
        for (int m = 0; m < 5; ++m) {
            int nr = r + 2 - m;
            if (nr < 0 || nr >= S_) continue;
            float wm = w5[m];
            const ushort* hr = R1 + nr * LSTR + q * 32;
#pragma unroll
            for (int c = 0; c < 4; ++c) {
                short8 v = *(const short8*)(hr + c * 8);
#pragma unroll
                for (int j = 0; j < 8; ++j) acc[c * 8 + j] += wm * bf2f((ushort)v[j]);
            }
        }
        ushort* op = R0 + r * LSTR + q * 32;  // own quarter-row only: race-free
#pragma unroll
        for (int c = 0; c < 4; ++c) {
            short8 v;
#pragma unroll
            for (int j = 0; j < 8; ++j) v[j] = (short)f2bf(acc[c * 8 + j]);
            *(short8*)(op + c * 8) = v;
        }
    }
    __syncthreads();

    // P5: ctx = nsum @ Wv + bv -> R1 (h dead)
    mm_stage<2>(R0, WvT, R1, wave, lane, bv, nullptr);
    __syncthreads();

    // P6: mid = relu(ctx @ W2 + b2) -> R0 cols 0..31 (14 (mt,nt) tasks / 8 waves)
    for (int t = wave; t < 14; t += 8) {
        int mt = t >> 1, nt = t & 1;
        int m0 = (mt < 6) ? mt * 16 : 84, n0 = nt * 16;
        short8 bfrag[4], afrag[4];
#pragma unroll
        for (int ks = 0; ks < 4; ++ks) {
            bfrag[ks] = *(const short8*)(W2T + (n0 + l15) * 128 + ks * 32 + quad * 8);
            afrag[ks] = *(const short8*)(R1 + (m0 + l15) * LSTR + ks * 32 + quad * 8);
        }
        float biasv = b2[n0 + l15];
        float4v acc = {0.f, 0.f, 0.f, 0.f};
#pragma unroll
        for (int ks = 0; ks < 4; ++ks)
            acc = __builtin_amdgcn_mfma_f32_16x16x32_bf16(afrag[ks], bfrag[ks], acc, 0, 0, 0);
#pragma unroll
        for (int i = 0; i < 4; ++i) {
            int row = m0 + quad * 4 + i;
            R0[row * LSTR + n0 + l15] = f2bf(fmaxf(acc[i] + biasv, 0.f));
        }
    }
    __syncthreads();

    // P7: out = mid @ W3 + b3 (K=32, N=2), vector math on 100 threads.
    if (tid < S_) {
        int r = tid;
        float o0 = b3[0], o1 = b3[1];
#pragma unroll
        for (int c8 = 0; c8 < 4; ++c8) {
            short8 v = *(const short8*)(R0 + r * LSTR + c8 * 8);
#pragma unroll
            for (int j = 0; j < 8; ++j) {
                float mv = bf2f((ushort)v[j]);
                int k = c8 * 8 + j;
                o0 += mv * W3[k * 2];
                o1 += mv * W3[k * 2 + 1];
            }
        }
        float* op = out + (size_t)b * (S_ * OUT_) + r * OUT_;
        op[0] = o0; op[1] = o1;
    }
}

// ---------------------------------------------------------------------------
extern "C" void kernel_launch(void* const* d_in, const int* in_sizes, int n_in,
                              void* d_out, int out_size, void* d_ws, size_t ws_size,
                              hipStream_t stream) {
    const float* x  = (const float*)d_in[0];
    const float* W1 = (const float*)d_in[1];
    const float* b1 = (const float*)d_in[2];
    const float* Wq = (const float*)d_in[3];
    const float* Wk = (const float*)d_in[4];
    const float* Wv = (const float*)d_in[5];
    const float* bv = (const float*)d_in[6];
    const float* W2 = (const float*)d_in[7];
    const float* b2 = (const float*)d_in[8];
    const float* W3 = (const float*)d_in[9];
    const float* b3 = (const float*)d_in[10];
    const float* pe = (const float*)d_in[11];

    float* out  = (float*)d_out;             // (B,S,2)
    float* wout = out + (size_t)P_ * OUT_;   // (B,S,1,5)

    ushort* W1T  = (ushort*)d_ws;            // [128][128] bf16
    ushort* WqkT = W1T + 16384;              // [128][128] bf16
    ushort* WvT  = WqkT + 16384;             // [128][128] bf16
    ushort* W2T  = WvT + 16384;              // [32][128]  bf16

    prep_kernel<<<160, 256, 0, stream>>>(W1, Wv, W2, Wq, Wk, W1T, WvT, W2T, WqkT);
    fused_kernel<<<B_, 512, 0, stream>>>(x, W1T, WqkT, WvT, W2T,
                                         b1, bv, b2, W3, b3, pe, out, wout);
}